// Round 9
// baseline (15.911 us; speedup 1.0000x reference)
//
#include <hip/hip_runtime.h>
#include <math.h>

#define PI_F 3.14159265358979323846f

// ---------------------------------------------------------------------------
// Amplitude-per-lane 4-qubit simulator (all-DPP exchanges + packed VOP3P
// math) + separate widened FC kernel.
//
// 16 lanes = 1 circuit; lane holds ONE complex amplitude. CNOTs fold into a
// compile-time lane relabeling f (GF(2)-linear); gate k exchanges with lane
// l ^ xm[k] and sign-selects by parity(l & sm[k]).
//
// ROUND-9: row_ror:8 (DPP 0x128) realizes xor-8 in ONE mov (rotate by half
// a 16-lane row == xor with 8). New exchange cost table:
//   1-mov: {1,2,3,7,8,15}   2-mov: {4,5,6,9,10,11,12,13,14}
// -> the former shfl_xor masks {9,10,11} leave the LDS pipe entirely; the
// gate loop is now 100% VALU (no lgkmcnt stalls on the serial gate chain).
// ---------------------------------------------------------------------------

struct Gates { int xm[84]; int sm[84]; int fin[4]; };

constexpr Gates make_gates() {
  Gates gt{};
  int F[4] = {1, 2, 4, 8};   // F[p]: bit_p(f(l)) = parity(l & F[p])
  int H[4] = {1, 2, 4, 8};   // rows of f^{-1}
  int ng = 0;
  auto cnot = [&](int c, int t) {
    const int pc = 3 - c, pt = 3 - t;
    F[pt] ^= F[pc];
    for (int p = 0; p < 4; ++p)
      if (H[p] & (1 << pt)) H[p] ^= (1 << pc);
  };
  auto gate = [&](int w) {
    const int p = 3 - w;
    int m = 0;
    for (int q = 0; q < 4; ++q)
      if (H[q] & (1 << p)) m |= 1 << q;   // m = f^{-1}(e_p)
    gt.xm[ng] = m; gt.sm[ng] = F[p]; ++ng;
  };
  for (int step = 0; step < 20; ++step)
    for (int j = 0; j < 4; ++j) {
      gate(j);
      cnot(0, 1); cnot(1, 2); cnot(2, 3); cnot(3, 0);
    }
  // RandomLayers stand-in: rx@3, ry@1, CNOT(0,2), rz@0, rx@2, CNOT(1,3)
  gate(3); gate(1); cnot(0, 2); gate(0); gate(2); cnot(1, 3);
  for (int p = 0; p < 4; ++p) gt.fin[p] = F[p];
  return gt;
}

constexpr Gates GT = make_gates();

// ---- DPP-based xor-shuffle (VALU pipe, max 2-mov chains) ------------------
template <int CTRL>
__device__ __forceinline__ float dppmov(float v) {
  return __int_as_float(
      __builtin_amdgcn_mov_dpp(__float_as_int(v), CTRL, 0xF, 0xF, true));
}

// xor-exchange across 16 lanes, all on the VALU:
//   quad_perm: xor1(0xB1) xor2(0x4E) xor3(0x1B)
//   row_half_mirror 0x141 = xor7 ; row_mirror 0x140 = xor15
//   row_ror:8 0x128 = xor8  (rotate by half-row == xor with 8)
template <int M>
__device__ __forceinline__ float sxor(float v) {
  if constexpr (M == 0) return v;
  else if constexpr (M == 1) return dppmov<0xB1>(v);
  else if constexpr (M == 2) return dppmov<0x4E>(v);
  else if constexpr (M == 3) return dppmov<0x1B>(v);
  else if constexpr (M == 7) return dppmov<0x141>(v);
  else if constexpr (M == 8) return dppmov<0x128>(v);
  else if constexpr (M == 15) return dppmov<0x140>(v);
  else if constexpr ((M & 8) != 0) {
    if constexpr ((M ^ 8) <= 3) return sxor<M ^ 8>(dppmov<0x128>(v));   // 9,10,11
    else return sxor<M ^ 15>(dppmov<0x140>(v));                          // 12,13,14
  }
  else return sxor<M ^ 7>(dppmov<0x141>(v));                             // 4,5,6
}

// Rot-symmetric gate: u00=(WR,WI), u01=(XR,XI), u10=(-XR,XI), u11=(WR,-WI).
//   nre = WR*re - cmi*im + cpr*pre - XI*pim
//   nim = WR*im + cmi*re + cpr*pim + XI*pre     (cmi=WI^sb, cpr=XR^sb)
// Packed (lo=nre, hi=nim) via 4 VOP3P ops with op_sel/neg_lo modifiers.
template <int XM, int SM>
__device__ __forceinline__ void apply_gate(float& re, float& im, unsigned P,
                                           float WR, float WI, float XR, float XI) {
  const float pre = sxor<XM>(re);
  const float pim = sxor<XM>(im);
  const unsigned sb = (P << (31 - SM)) & 0x80000000u;
  float2 s;  s.x = re;   s.y = im;
  float2 p2; p2.x = pre; p2.y = pim;
  float2 wx; wx.x = WR;  wx.y = XI;
  float2 cc;
  cc.x = __uint_as_float(__float_as_uint(WI) ^ sb);
  cc.y = __uint_as_float(__float_as_uint(XR) ^ sb);
  float2 d;
  asm("v_pk_mul_f32 %0, %1, %3 op_sel:[0,0] op_sel_hi:[1,0]\n\t"
      "v_pk_fma_f32 %0, %1, %4, %0 op_sel:[1,0,0] op_sel_hi:[0,0,1] neg_lo:[0,1,0]\n\t"
      "v_pk_fma_f32 %0, %2, %4, %0 op_sel:[0,1,0] op_sel_hi:[1,1,1]\n\t"
      "v_pk_fma_f32 %0, %2, %3, %0 op_sel:[1,1,0] op_sel_hi:[0,1,1] neg_lo:[0,1,0]"
      : "=&v"(d)
      : "v"(s), "v"(p2), "v"(wx), "v"(cc));
  re = d.x; im = d.y;
}

// Compile-time-unrolled 80-gate main loop (masks must be template args).
template <int K>
struct Loop80 {
  static __device__ __forceinline__ void run(float& re, float& im, unsigned P,
      const float (&wr)[4], const float (&wi)[4],
      const float (&xr)[4], const float (&xi)[4]) {
    constexpr int g = (K >> 2) & 3;
    apply_gate<GT.xm[K], GT.sm[K]>(re, im, P, wr[g], wi[g], xr[g], xi[g]);
    Loop80<K + 1>::run(re, im, P, wr, wi, xr, xi);
  }
};
template <>
struct Loop80<80> {
  static __device__ __forceinline__ void run(float&, float&, unsigned,
      const float (&)[4], const float (&)[4],
      const float (&)[4], const float (&)[4]) {}
};

__global__ __launch_bounds__(64) void qcnn_circuit_kernel(
    const float* __restrict__ images,   // (64,1,28,28)
    const float* __restrict__ rp,       // (4,)
    float* __restrict__ qout)           // (64*196*4,)
{
  const int gtid = blockIdx.x * 64 + threadIdx.x;
  const int c    = gtid >> 4;          // circuit id, 0..12543
  const int l16  = gtid & 15;          // lane within circuit = initial amp idx

  const int b  = c / 196;
  const int pi = c - b * 196;
  const int pj = pi / 14;
  const int pk = pi - pj * 14;

  const float* img = images + b * 784 + (2 * pj) * 28 + 2 * pk;
  const float2 r0 = *reinterpret_cast<const float2*>(img);
  const float2 r1 = *reinterpret_cast<const float2*>(img + 28);
  float px[4];
  px[0] = r0.x * PI_F;
  px[1] = r0.y * PI_F;
  px[2] = r1.x * PI_F;
  px[3] = r1.y * PI_F;

  // Per-lane parity table: bit_m(P) = parity(l16 & m).
  unsigned P = 0;
  if (l16 & 1) P ^= 0xAAAAu;
  if (l16 & 2) P ^= 0xCCCCu;
  if (l16 & 4) P ^= 0xF0F0u;
  if (l16 & 8) P ^= 0xFF00u;

  // 4 distinct Rot matrices (GROUP_IDX period 4).
  float wr[4], wi[4], xr[4], xi[4];
  {
    const int GIphi[4] = {0, 3, 2, 1};
    const int GIth [4] = {1, 0, 3, 2};
    const int GIom [4] = {2, 1, 0, 3};
#pragma unroll
    for (int g = 0; g < 4; ++g) {
      const float phi = px[GIphi[g]], th = px[GIth[g]], om = px[GIom[g]];
      const float a = 0.5f * (phi + om), d = 0.5f * (phi - om), h = 0.5f * th;
      const float sa = __sinf(a), ca = __cosf(a);
      const float sd = __sinf(d), cd = __cosf(d);
      const float st = __sinf(h), ct = __cosf(h);
      wr[g] =  ca * ct;  wi[g] = -sa * ct;   // u00
      xr[g] = -cd * st;  xi[g] = -sd * st;   // u01
    }
  }

  float re = (l16 == 0) ? 1.f : 0.f;
  float im = 0.f;

  Loop80<0>::run(re, im, P, wr, wi, xr, xi);

  // Final gates 80..83: RX(rp0)@3, RY(rp1)@1, RZ(rp2)@0, RX(rp3)@2.
  {
    const float s0 = __sinf(0.5f * rp[0]), c0 = __cosf(0.5f * rp[0]);
    apply_gate<GT.xm[80], GT.sm[80]>(re, im, P, c0, 0.f, 0.f, -s0);
    const float s1 = __sinf(0.5f * rp[1]), c1 = __cosf(0.5f * rp[1]);
    apply_gate<GT.xm[81], GT.sm[81]>(re, im, P, c1, 0.f, -s1, 0.f);
    const float s2 = __sinf(0.5f * rp[2]), c2 = __cosf(0.5f * rp[2]);
    apply_gate<GT.xm[82], GT.sm[82]>(re, im, P, c2, -s2, 0.f, 0.f);
    const float s3 = __sinf(0.5f * rp[3]), c3 = __cosf(0.5f * rp[3]);
    apply_gate<GT.xm[83], GT.sm[83]>(re, im, P, c3, 0.f, 0.f, -s3);
  }

  // PauliZ expvals; sign for wire j = parity(l & fin[3-j]).
  const float pr = re * re + im * im;
  float e0 = __uint_as_float(__float_as_uint(pr) ^ ((P << (31 - GT.fin[3])) & 0x80000000u));
  float e1 = __uint_as_float(__float_as_uint(pr) ^ ((P << (31 - GT.fin[2])) & 0x80000000u));
  float e2 = __uint_as_float(__float_as_uint(pr) ^ ((P << (31 - GT.fin[1])) & 0x80000000u));
  float e3 = __uint_as_float(__float_as_uint(pr) ^ ((P << (31 - GT.fin[0])) & 0x80000000u));
  // 16-lane reduce on VALU: after xor1,xor2 folds the quads are uniform, so
  // xor7 folds bit2; then ror8 folds bit3.
  e0 += dppmov<0xB1>(e0); e0 += dppmov<0x4E>(e0); e0 += dppmov<0x141>(e0); e0 += dppmov<0x128>(e0);
  e1 += dppmov<0xB1>(e1); e1 += dppmov<0x4E>(e1); e1 += dppmov<0x141>(e1); e1 += dppmov<0x128>(e1);
  e2 += dppmov<0xB1>(e2); e2 += dppmov<0x4E>(e2); e2 += dppmov<0x141>(e2); e2 += dppmov<0x128>(e2);
  e3 += dppmov<0xB1>(e3); e3 += dppmov<0x4E>(e3); e3 += dppmov<0x141>(e3); e3 += dppmov<0x128>(e3);
  float v = e0;
  v = (l16 == 1) ? e1 : v;
  v = (l16 == 2) ? e2 : v;
  v = (l16 == 3) ? e3 : v;
  if (l16 < 4) qout[c * 4 + l16] = v;
}

// ---------------------------------------------------------------------------
// FC (10x784) + log_softmax. One block (256 threads) per image:
// thread t<196 handles one float4 chunk -> single load round. (r8 verbatim)
// ---------------------------------------------------------------------------
__global__ __launch_bounds__(256) void qcnn_fc_kernel(
    const float* __restrict__ q,     // (64,784)
    const float* __restrict__ fcw,   // (10,784)
    const float* __restrict__ fcb,   // (10,)
    float* __restrict__ out)         // (64,10)
{
  const int b = blockIdx.x;
  const int t = threadIdx.x;

  float acc[10];
#pragma unroll
  for (int o = 0; o < 10; ++o) acc[o] = 0.f;

  if (t < 196) {
    const float4 qv = reinterpret_cast<const float4*>(q + b * 784)[t];
    const float4* w4 = reinterpret_cast<const float4*>(fcw);
#pragma unroll
    for (int o = 0; o < 10; ++o) {
      const float4 wv = w4[o * 196 + t];
      acc[o] += qv.x * wv.x + qv.y * wv.y + qv.z * wv.z + qv.w * wv.w;
    }
  }

  // 64-lane wave reduce.
#pragma unroll
  for (int o = 0; o < 10; ++o) {
#pragma unroll
    for (int off = 32; off > 0; off >>= 1)
      acc[o] += __shfl_xor(acc[o], off);
  }

  __shared__ float ws[4][10];
  const int wid = t >> 6;
  if ((t & 63) == 0) {
#pragma unroll
    for (int o = 0; o < 10; ++o) ws[wid][o] = acc[o];
  }
  __syncthreads();

  if (t < 16) {
    float lgv = -1e30f;
    if (t < 10)
      lgv = ws[0][t] + ws[1][t] + ws[2][t] + ws[3][t] + fcb[t];
    float mx = lgv;
#pragma unroll
    for (int s = 1; s < 16; s <<= 1) mx = fmaxf(mx, __shfl_xor(mx, s));
    float ex = (t < 10) ? __expf(lgv - mx) : 0.f;
    float se = ex;
#pragma unroll
    for (int s = 1; s < 16; s <<= 1) se += __shfl_xor(se, s);
    if (t < 10) out[b * 10 + t] = lgv - mx - __logf(se);
  }
}

// ---------------------------------------------------------------------------

extern "C" void kernel_launch(void* const* d_in, const int* in_sizes, int n_in,
                              void* d_out, int out_size, void* d_ws, size_t ws_size,
                              hipStream_t stream) {
  const float* images = (const float*)d_in[0];   // 64*1*28*28
  const float* rp     = (const float*)d_in[1];   // 4
  const float* fcw    = (const float*)d_in[2];   // 10*784
  const float* fcb    = (const float*)d_in[3];   // 10
  float* out = (float*)d_out;                    // 64*10
  float* q   = (float*)d_ws;                     // 64*196*4 floats

  // 12544 circuits x 16 lanes = 200704 threads = 3136 blocks x 64
  qcnn_circuit_kernel<<<3136, 64, 0, stream>>>(images, rp, q);
  qcnn_fc_kernel<<<64, 256, 0, stream>>>(q, fcw, fcb, out);
}